// Round 14
// baseline (149.529 us; speedup 1.0000x reference)
//
#include <hip/hip_runtime.h>
#include <stdint.h>

// LinearBin: out = x @ sign(W)^T + bias   (B=131072, IN=OUT=512, fp32)
// v14: flow-halving. BM=128, BN=512, 8 waves x (64x128 wave-tile).
//      Halves A-LDS read traffic (2MB/CU) and B L2 traffic (512MB total)
//      vs v8, at the cost of 1 block/CU (128KB LDS). Whole x-strip staged
//      once as bf16 (16-deep XOR swizzle, v13-verified conflict-free),
//      ONE barrier, v8's K-loop register rotation (A +1, B +2), bias in
//      acc, direct epilogue stores.

#define BATCH   131072
#define IN_F    512
#define OUT_F   512
#define BM      128
#define NKT     32            // K-steps of 16

using f32x4  = __attribute__((ext_vector_type(4))) float;
using f32x16 = __attribute__((ext_vector_type(16))) float;
using short8 = __attribute__((ext_vector_type(8))) short;
using usv8   = __attribute__((ext_vector_type(8))) unsigned short;
using u32    = uint32_t;

// ---------------- prep: binarize W into 32x32x16-fragment-major bf16 --------
// (verified r6/r8)  wf[((kt*16+nf)*64+l)*8+j] = sign(W[nf*32+(l&31)][kt*16+(l>>5)*8+j])
__global__ void prep_w(const float* __restrict__ W, unsigned short* __restrict__ wf) {
    int t = blockIdx.x * blockDim.x + threadIdx.x; // 32768 threads
    int l  = t & 63;
    int nf = (t >> 6) & 15;
    int kt = t >> 10;
    int n = nf * 32 + (l & 31);
    int k = kt * 16 + ((l >> 5) << 3);
    const float* src = W + (size_t)n * IN_F + k;
    f32x4 w0 = *(const f32x4*)(src);
    f32x4 w1 = *(const f32x4*)(src + 4);
    usv8 o;
#pragma unroll
    for (int j = 0; j < 4; ++j) {
        o[j]     = (w0[j] >= 0.0f) ? 0x3F80u : 0xBF80u; // +1.0 / -1.0 bf16
        o[j + 4] = (w1[j] >= 0.0f) ? 0x3F80u : 0xBF80u;
    }
    *(usv8*)(wf + (size_t)t * 8) = o;
}

// ---------------- GEMM: one barrier, then barrier-free K-loop ----------------
__global__ __launch_bounds__(512, 2) void gemm_bin(
    const float* __restrict__ X, const unsigned short* __restrict__ WF,
    const float* __restrict__ bias, float* __restrict__ out) {

    // 128 rows x 512 bf16, row stride 1KB; 16B slots XOR-swizzled by (row&15).
    __shared__ __align__(16) unsigned short lds[BM * IN_F]; // 128KB

    const int tid  = threadIdx.x;
    const int lane = tid & 63;
    const int wv   = tid >> 6;
    const int wm   = wv >> 2;               // 0..1 -> 64-row half
    const int wn   = wv & 3;                // 0..3 -> 128-col strip
    const int m0   = blockIdx.x * BM;       // grid = 1024

    // ---- stage whole 128x512 x-strip as bf16 (once) ----
    {
        const int r  = tid >> 2;            // 0..127
        const int sg = tid & 3;             // 128-float quarter of the row
        const float* xr = X + (size_t)(m0 + r) * IN_F + sg * 128;
        char* lrow = (char*)lds + r * 1024;
        const int msk = (r & 15) << 4;
#pragma unroll
        for (int p = 0; p < 16; ++p) {
            f32x4 a = *(const f32x4*)(xr + p * 8);
            f32x4 b = *(const f32x4*)(xr + p * 8 + 4);
            u32 w0, w1, w2, w3;
            asm("v_cvt_pk_bf16_f32 %0, %1, %2" : "=v"(w0) : "v"(a[0]), "v"(a[1]));
            asm("v_cvt_pk_bf16_f32 %0, %1, %2" : "=v"(w1) : "v"(a[2]), "v"(a[3]));
            asm("v_cvt_pk_bf16_f32 %0, %1, %2" : "=v"(w2) : "v"(b[0]), "v"(b[1]));
            asm("v_cvt_pk_bf16_f32 %0, %1, %2" : "=v"(w3) : "v"(b[2]), "v"(b[3]));
            union { u32 w[4]; usv8 v; } pk;
            pk.w[0] = w0; pk.w[1] = w1; pk.w[2] = w2; pk.w[3] = w3;
            // slot = sg*16 + p; byte = slot*16 ^ msk (carry-free: disjoint bits)
            *(usv8*)(lrow + ((sg * 256 + p * 16) ^ msk)) = pk.v;
        }
    }

    // ---- bias -> accumulator init (C/D col = lane&31; bias is col-only) ----
    f32x16 acc[2][4];
#pragma unroll
    for (int fn = 0; fn < 4; ++fn) {
        const float bv = bias[wn * 128 + fn * 32 + (lane & 31)];
#pragma unroll
        for (int rg = 0; rg < 2; ++rg)
#pragma unroll
            for (int r = 0; r < 16; ++r) acc[rg][fn][r] = bv;
    }
    __syncthreads();   // the ONLY barrier

    // ---- A geometry: row = wm*64 + rg*32 + (l&31); (row&15)==(l&15) ----
    const int arow  = (wm * 64 + (lane & 31)) * 1024;
    const int ak4   = (lane >> 5) << 4;
    const int aswz  = (lane & 15) << 4;
    const char* lptr = (const char*)lds;

#define LDA(dst, kt_)                                                          \
    {                                                                          \
        const int koff_ = ((kt_) * 32 + ak4) ^ aswz;                           \
        dst[0] = *(const short8*)(lptr + arow + koff_);                        \
        dst[1] = *(const short8*)(lptr + arow + 32768 + koff_);                \
    }

    // ---- B geometry: fragment-major; nf = wn*4 + fn ----
    const short8* wb = (const short8*)(WF) + ((size_t)(wn * 4) * 64 + lane);
#define LDB(dst, kt_)                                                          \
    {                                                                          \
        _Pragma("unroll")                                                      \
        for (int fn = 0; fn < 4; ++fn)                                         \
            dst[fn] = wb[(kt_) * 1024 + fn * 64];                              \
    }

    short8 af[2][2], bf[2][4];
    LDA(af[0], 0);
    LDB(bf[0], 0);
    LDB(bf[1], 1);

#pragma unroll
    for (int kt = 0; kt < NKT; ++kt) {
        const int cur = kt & 1;
        if (kt < NKT - 1) LDA(af[cur ^ 1], kt + 1);
        __builtin_amdgcn_s_setprio(1);
#pragma unroll
        for (int rg = 0; rg < 2; ++rg)
#pragma unroll
            for (int fn = 0; fn < 4; ++fn)
                acc[rg][fn] = __builtin_amdgcn_mfma_f32_32x32x16_bf16(
                    af[cur][rg], bf[cur][fn], acc[rg][fn], 0, 0, 0);
        __builtin_amdgcn_s_setprio(0);
        if (kt < NKT - 2) LDB(bf[cur], kt + 2);   // 2-ahead, post-consume slot
    }
#undef LDA
#undef LDB

    // ---- epilogue: direct stores (bias already in acc) ----
    // C/D: col = lane&31, row = (r&3) + 8*(r>>2) + 4*(lane>>5)
    const int c     = lane & 31;
    const int rbase = (lane >> 5) << 2;
#pragma unroll
    for (int rg = 0; rg < 2; ++rg)
#pragma unroll
        for (int fn = 0; fn < 4; ++fn)
#pragma unroll
            for (int r = 0; r < 16; ++r) {
                const int row = wm * 64 + rg * 32 + (r & 3) + 8 * (r >> 2) + rbase;
                out[(size_t)(m0 + row) * OUT_F + wn * 128 + fn * 32 + c] =
                    acc[rg][fn][r];
            }
}

extern "C" void kernel_launch(void* const* d_in, const int* in_sizes, int n_in,
                              void* d_out, int out_size, void* d_ws, size_t ws_size,
                              hipStream_t stream) {
    const float* X    = (const float*)d_in[0];
    const float* W    = (const float*)d_in[1];
    const float* bias = (const float*)d_in[2];
    float* o          = (float*)d_out;
    unsigned short* wf = (unsigned short*)d_ws; // 512KB fragment-major binarized W

    hipLaunchKernelGGL(prep_w, dim3(128), dim3(256), 0, stream, W, wf);
    hipLaunchKernelGGL(gemm_bin, dim3(BATCH / BM), dim3(512), 0, stream,
                       X, wf, bias, o);
}